// Round 10
// baseline (258.678 us; speedup 1.0000x reference)
//
#include <hip/hip_runtime.h>
#include <hip/hip_bf16.h>
#include <math.h>

// Problem constants (fixed by reference setup_inputs)
constexpr int Bsz  = 2;
constexpr int Lseq = 1024;
constexpr int Dmod = 1024;   // d
constexpr int Din  = 2048;   // Di = 2*d
constexpr int NST  = 16;     // D_STATE
constexpr int RNK  = 64;     // DT_RANK
constexpr int Tt   = Bsz * Lseq;  // 2048 tokens
constexpr int NC   = 128;    // scan chunks (R10: 64->128 for occupancy)
constexpr int LC   = Lseq / NC;  // 8 timesteps per chunk

constexpr float L2E = 1.44269504088896341f;   // log2(e)
constexpr float LN2 = 0.69314718055994531f;   // ln(2)

typedef short bf16x8 __attribute__((ext_vector_type(8)));
typedef float f32x4  __attribute__((ext_vector_type(4)));

// fast transcendentals: v_exp_f32 is native 2^x
__device__ __forceinline__ float sigmoid_f(float x) {
    return __builtin_amdgcn_rcpf(1.f + exp2f(-x * L2E));
}
__device__ __forceinline__ float softplus_f(float x) {
    return fmaxf(x, 0.f) + LN2 * log2f(1.f + exp2f(-fabsf(x) * L2E));
}
__device__ __forceinline__ unsigned short f2bf(float f) {
    union { float f; unsigned int u; } v; v.f = f;
    unsigned int r = v.u + 0x7fffu + ((v.u >> 16) & 1u);   // RNE
    return (unsigned short)(r >> 16);
}
__device__ __forceinline__ float bf2f(unsigned short u) {
    union { unsigned int u; float f; } v; v.u = ((unsigned int)u) << 16;
    return v.f;
}

// ---------------- LayerNorm -> bf16 h ----------------
__global__ __launch_bounds__(256) void ln_kernel(
    const float* __restrict__ x, const float* __restrict__ g,
    const float* __restrict__ bta, unsigned short* __restrict__ h)
{
    int row = blockIdx.x;
    const float4* xr = (const float4*)(x + (size_t)row * Dmod);
    float4 v = xr[threadIdx.x];
    float s  = v.x + v.y + v.z + v.w;
    float ss = v.x*v.x + v.y*v.y + v.z*v.z + v.w*v.w;
    #pragma unroll
    for (int o = 1; o < 64; o <<= 1) {
        s  += __shfl_xor(s, o, 64);
        ss += __shfl_xor(ss, o, 64);
    }
    __shared__ float red0[4], red1[4];
    int wid = threadIdx.x >> 6;
    if ((threadIdx.x & 63) == 0) { red0[wid] = s; red1[wid] = ss; }
    __syncthreads();
    s  = red0[0] + red0[1] + red0[2] + red0[3];
    ss = red1[0] + red1[1] + red1[2] + red1[3];
    float mu  = s * (1.f / Dmod);
    float var = ss * (1.f / Dmod) - mu * mu;
    float rs  = rsqrtf(var + 1e-5f);
    float4 gv = ((const float4*)g)[threadIdx.x];
    float4 bv = ((const float4*)bta)[threadIdx.x];
    ushort4 o;
    o.x = f2bf((v.x - mu) * rs * gv.x + bv.x);
    o.y = f2bf((v.y - mu) * rs * gv.y + bv.y);
    o.z = f2bf((v.z - mu) * rs * gv.z + bv.z);
    o.w = f2bf((v.w - mu) * rs * gv.w + bv.w);
    ((ushort4*)(h + (size_t)row * Dmod))[threadIdx.x] = o;
}

// ---- merged transpose+cast for all 4 weights: in[K,N] f32 -> out[Npad,K] bf16 ----
__global__ __launch_bounds__(256) void transpose_all(
    const float* __restrict__ W_in,   unsigned short* __restrict__ WinT,
    const float* __restrict__ W_out,  unsigned short* __restrict__ WoutT,
    const float* __restrict__ W_xprj, unsigned short* __restrict__ WxprjT,
    const float* __restrict__ W_dt,   unsigned short* __restrict__ WdtT)
{
    int bid = blockIdx.x;
    const float* in; unsigned short* outp; int K, N, Npad, bx, by;
    if (bid < 1024)      { in = W_in;   outp = WinT;   K = Dmod; N = 2*Din; Npad = 2*Din; bx = bid & 63; by = bid >> 6; }
    else if (bid < 1536) { bid -= 1024; in = W_out;  outp = WoutT;  K = Din;  N = Dmod;  Npad = Dmod;  bx = bid & 15; by = bid >> 4; }
    else if (bid < 1600) { bid -= 1536; in = W_xprj; outp = WxprjT; K = Din;  N = 96;    Npad = 128;   bx = bid & 1;  by = bid >> 1; }
    else                 { bid -= 1600; in = W_dt;   outp = WdtT;   K = RNK;  N = Din;   Npad = Din;   bx = bid;      by = 0; }

    __shared__ float tile[64][65];
    int bk = by * 64, bn = bx * 64;
    #pragma unroll
    for (int i = 0; i < 16; i++) {
        int k = (threadIdx.x >> 6) + i * 4;
        int n = threadIdx.x & 63;
        int gk = bk + k, gn = bn + n;
        tile[k][n] = (gk < K && gn < N) ? in[(size_t)gk * N + gn] : 0.f;
    }
    __syncthreads();
    #pragma unroll
    for (int i = 0; i < 16; i++) {
        int n = (threadIdx.x >> 6) + i * 4;
        int k = threadIdx.x & 63;
        int gn = bn + n, gk = bk + k;
        if (gn < Npad && gk < K)
            outp[(size_t)gn * K + gk] = f2bf(tile[k][n]);
    }
}

// ---------------- bf16 MFMA GEMM, double-buffered (T3-min 2-phase) ----------------
template<int EPI, int BF16OUT>
__global__ __launch_bounds__(256) void gemm_mfma(
    const unsigned short* __restrict__ A, int lda,
    const unsigned short* __restrict__ Bt, int ldb,
    void* __restrict__ Cout, int ldc,
    const float* __restrict__ resid, const float* __restrict__ bias,
    int M, int N, int Ksub, size_t pstride)
{
    __shared__ unsigned short As[2][128 * 32];
    __shared__ unsigned short Bs[2][128 * 32];
    int tid = threadIdx.x;
    int bm = blockIdx.y * 128, bn = blockIdx.x * 128;
    int kbase = blockIdx.z * Ksub;
    int lane = tid & 63, wid = tid >> 6;
    int wm = (wid & 1) * 64, wn = (wid >> 1) * 64;

    f32x4 acc[4][4] = {};

    int row = tid >> 2;
    int kb  = (tid & 3) * 8;
    unsigned lbase = (unsigned)wid * 1024;

    const unsigned short* Ab0 = A  + (size_t)(bm + row)      * lda + kbase + kb;
    const unsigned short* Ab1 = A  + (size_t)(bm + 64 + row) * lda + kbase + kb;
    const unsigned short* Bb0 = Bt + (size_t)(bn + row)      * ldb + kbase + kb;
    const unsigned short* Bb1 = Bt + (size_t)(bn + 64 + row) * ldb + kbase + kb;

#define STAGE(bufsel, koff) do {                                                          \
    __builtin_amdgcn_global_load_lds(                                                     \
        (const __attribute__((address_space(1))) unsigned int*)(Ab0 + (koff)),            \
        (__attribute__((address_space(3))) unsigned int*)((char*)As + (bufsel) * 8192 + lbase), 16, 0, 0); \
    __builtin_amdgcn_global_load_lds(                                                     \
        (const __attribute__((address_space(1))) unsigned int*)(Ab1 + (koff)),            \
        (__attribute__((address_space(3))) unsigned int*)((char*)As + (bufsel) * 8192 + 4096 + lbase), 16, 0, 0); \
    __builtin_amdgcn_global_load_lds(                                                     \
        (const __attribute__((address_space(1))) unsigned int*)(Bb0 + (koff)),            \
        (__attribute__((address_space(3))) unsigned int*)((char*)Bs + (bufsel) * 8192 + lbase), 16, 0, 0); \
    __builtin_amdgcn_global_load_lds(                                                     \
        (const __attribute__((address_space(1))) unsigned int*)(Bb1 + (koff)),            \
        (__attribute__((address_space(3))) unsigned int*)((char*)Bs + (bufsel) * 8192 + 4096 + lbase), 16, 0, 0); \
} while (0)

    STAGE(0, 0);
    __syncthreads();

    int nt = Ksub / 32;
    int cur = 0;
    for (int t = 0; t < nt; ++t) {
        if (t + 1 < nt) STAGE(cur ^ 1, (t + 1) * 32);
        bf16x8 af[4], bfr[4];
        #pragma unroll
        for (int m = 0; m < 4; m++) {
            int r = wm + m * 16 + (lane & 15);
            af[m] = *(const bf16x8*)((const char*)As + cur * 8192 + r * 64 + (lane >> 4) * 16);
        }
        #pragma unroll
        for (int n = 0; n < 4; n++) {
            int r = wn + n * 16 + (lane & 15);
            bfr[n] = *(const bf16x8*)((const char*)Bs + cur * 8192 + r * 64 + (lane >> 4) * 16);
        }
        #pragma unroll
        for (int m = 0; m < 4; m++)
            #pragma unroll
            for (int n = 0; n < 4; n++)
                acc[m][n] = __builtin_amdgcn_mfma_f32_16x16x32_bf16(af[m], bfr[n], acc[m][n], 0, 0, 0);
        __syncthreads();
        cur ^= 1;
    }
#undef STAGE

    size_t zoff = (size_t)blockIdx.z * pstride;
    #pragma unroll
    for (int m = 0; m < 4; m++) {
        int gm0 = bm + wm + m * 16 + (lane >> 4) * 4;
        #pragma unroll
        for (int n = 0; n < 4; n++) {
            int gn = bn + wn + n * 16 + (lane & 15);
            #pragma unroll
            for (int r = 0; r < 4; r++) {
                int gm = gm0 + r;
                float v = acc[m][n][r];
                if (EPI == 1) v = softplus_f(v + bias[gn]);
                else if (EPI == 2) v += resid[(size_t)gm * ldc + gn];
                if (BF16OUT)
                    ((unsigned short*)Cout)[zoff + (size_t)gm * ldc + gn] = f2bf(v);
                else
                    ((float*)Cout)[zoff + (size_t)gm * ldc + gn] = v;
            }
        }
    }
}

// ---------------- split-K reduces ----------------
__global__ __launch_bounds__(256) void reduce_xproj(
    const float* __restrict__ part, unsigned short* __restrict__ out)
{
    int idx = blockIdx.x * 256 + threadIdx.x;    // < Tt*128
    float s = 0.f;
    #pragma unroll
    for (int z = 0; z < 8; z++) s += part[(size_t)z * Tt * 128 + idx];
    out[idx] = f2bf(s);
}

__global__ __launch_bounds__(256) void reduce_out(
    const float* __restrict__ part, const float* __restrict__ resid,
    float* __restrict__ out)
{
    int idx = blockIdx.x * 256 + threadIdx.x;    // < Tt*Dmod/4
    float4 p0 = ((const float4*)part)[idx];
    float4 p1 = ((const float4*)(part + (size_t)Tt * Dmod))[idx];
    float4 rv = ((const float4*)resid)[idx];
    float4 o;
    o.x = p0.x + p1.x + rv.x;
    o.y = p0.y + p1.y + rv.y;
    o.z = p0.z + p1.z + rv.z;
    o.w = p0.w + p1.w + rv.w;
    ((float4*)out)[idx] = o;
}

// ------- Causal depthwise conv (K=4) + SiLU, 8 channels/thread (bf16x8) -------
__global__ __launch_bounds__(256) void conv_silu_kernel(
    const unsigned short* __restrict__ xz, const float* __restrict__ w,
    const float* __restrict__ cb, unsigned short* __restrict__ xcb)
{
    size_t idx = (size_t)blockIdx.x * 256 + threadIdx.x;   // < Tt*Din/8
    int di8 = (idx * 8) % Din;
    int t   = (idx * 8 / Din) % Lseq;
    int b   = idx * 8 / ((size_t)Din * Lseq);
    const unsigned short* base = xz + (size_t)b * Lseq * (2 * Din) + di8;

    float acc[8];
    float4 cb0 = *(const float4*)(cb + di8);
    float4 cb1 = *(const float4*)(cb + di8 + 4);
    acc[0]=cb0.x; acc[1]=cb0.y; acc[2]=cb0.z; acc[3]=cb0.w;
    acc[4]=cb1.x; acc[5]=cb1.y; acc[6]=cb1.z; acc[7]=cb1.w;

    float4 wv[8];
    #pragma unroll
    for (int j = 0; j < 8; j++) wv[j] = *(const float4*)(w + (di8 + j) * 4);

    #pragma unroll
    for (int k = 0; k < 4; k++) {
        int tt = t - 3 + k;
        if (tt >= 0) {
            bf16x8 rowv = *(const bf16x8*)(base + (size_t)tt * (2 * Din));
            #pragma unroll
            for (int j = 0; j < 8; j++) {
                float wk = (&wv[j].x)[k];
                acc[j] = fmaf(wk, bf2f((unsigned short)rowv[j]), acc[j]);
            }
        }
    }
    bf16x8 outv;
    #pragma unroll
    for (int j = 0; j < 8; j++) {
        float v = acc[j] * sigmoid_f(acc[j]);
        outv[j] = (short)f2bf(v);
    }
    *(bf16x8*)(xcb + idx * 8) = outv;
}

// ---------------- Selective scan: chunk-parallel 3-pass ----------------
__global__ __launch_bounds__(256) void scan_a(
    const unsigned short* __restrict__ delta, const unsigned short* __restrict__ xc,
    const unsigned short* __restrict__ dbc, const float* __restrict__ A_log,
    unsigned short* __restrict__ Sloc, float* __restrict__ sumd_buf)
{
    int tid = threadIdx.x;
    int di = blockIdx.x * 256 + tid;
    int c  = blockIdx.y, b = blockIdx.z;
    int t0 = c * LC;
    __shared__ float Bs[LC][16];
    for (int i = tid; i < LC * 16; i += 256) {
        int tl = i >> 4, n = i & 15;
        Bs[tl][n] = bf2f(dbc[(size_t)(b * Lseq + t0 + tl) * 128 + RNK + n]);
    }
    float An2[16];
    #pragma unroll
    for (int n = 0; n < 16; n++) An2[n] = -expf(A_log[di * NST + n]) * L2E;
    __syncthreads();

    float s[16] = {};
    float sd = 0.f;
    const unsigned short* dp = delta + (size_t)(b * Lseq + t0) * Din + di;
    const unsigned short* up = xc    + (size_t)(b * Lseq + t0) * Din + di;
    #pragma unroll
    for (int t = 0; t < LC; t++) {
        float dlt = bf2f(dp[(size_t)t * Din]);
        float u   = bf2f(up[(size_t)t * Din]);
        sd += dlt;
        float du = dlt * u;
        const float4* brow = (const float4*)&Bs[t][0];
        #pragma unroll
        for (int j = 0; j < 4; j++) {
            float4 bv = brow[j];
            s[4*j+0] = fmaf(exp2f(dlt * An2[4*j+0]), s[4*j+0], du * bv.x);
            s[4*j+1] = fmaf(exp2f(dlt * An2[4*j+1]), s[4*j+1], du * bv.y);
            s[4*j+2] = fmaf(exp2f(dlt * An2[4*j+2]), s[4*j+2], du * bv.z);
            s[4*j+3] = fmaf(exp2f(dlt * An2[4*j+3]), s[4*j+3], du * bv.w);
        }
    }
    size_t base = (size_t)((b * NC + c) * 16) * Din + di;
    #pragma unroll
    for (int n = 0; n < 16; n++) Sloc[base + (size_t)n * Din] = f2bf(s[n]);
    sumd_buf[(size_t)(b * NC + c) * Din + di] = sd;
}

__global__ __launch_bounds__(256) void scan_b(
    const float* __restrict__ A_log, const float* __restrict__ sumd_buf,
    unsigned short* __restrict__ Sloc)
{
    int tid = threadIdx.x;
    int di = blockIdx.x * 256 + tid;
    int n  = blockIdx.y, b = blockIdx.z;
    float An2 = -expf(A_log[di * NST + n]) * L2E;
    float s = 0.f;
    #pragma unroll 4
    for (int c = 0; c < NC; c++) {
        size_t idx = (size_t)((b * NC + c) * 16 + n) * Din + di;
        float sl = bf2f(Sloc[idx]);
        float sd = sumd_buf[(size_t)(b * NC + c) * Din + di];
        Sloc[idx] = f2bf(s);                  // s_in for chunk c
        s = fmaf(exp2f(An2 * sd), s, sl);     // chunk-final state
    }
}

__global__ __launch_bounds__(256) void scan_c(
    const unsigned short* __restrict__ delta, const unsigned short* __restrict__ xc,
    const unsigned short* __restrict__ xz, const unsigned short* __restrict__ dbc,
    const float* __restrict__ A_log, const float* __restrict__ Dp,
    const unsigned short* __restrict__ Sloc,  unsigned short* __restrict__ yz)
{
    int tid = threadIdx.x;
    int di = blockIdx.x * 256 + tid;
    int c  = blockIdx.y, b = blockIdx.z;
    int t0 = c * LC;
    __shared__ float Bs[LC][16], Cs[LC][16];
    for (int i = tid; i < LC * 16; i += 256) {
        int tl = i >> 4, n = i & 15;
        size_t rb = (size_t)(b * Lseq + t0 + tl) * 128;
        Bs[tl][n] = bf2f(dbc[rb + RNK + n]);
        Cs[tl][n] = bf2f(dbc[rb + RNK + NST + n]);
    }
    float An2[16];
    #pragma unroll
    for (int n = 0; n < 16; n++) An2[n] = -expf(A_log[di * NST + n]) * L2E;
    __syncthreads();

    float s[16];
    size_t sbase = (size_t)((b * NC + c) * 16) * Din + di;
    #pragma unroll
    for (int n = 0; n < 16; n++) s[n] = bf2f(Sloc[sbase + (size_t)n * Din]);
    float Dv = Dp[di];

    const unsigned short* dp = delta + (size_t)(b * Lseq + t0) * Din + di;
    const unsigned short* up = xc    + (size_t)(b * Lseq + t0) * Din + di;
    const unsigned short* zp = xz    + (size_t)(b * Lseq + t0) * (2 * Din) + Din + di;
    unsigned short* yp = yz + (size_t)(b * Lseq + t0) * Din + di;
    #pragma unroll
    for (int t = 0; t < LC; t++) {
        float dlt = bf2f(dp[(size_t)t * Din]);
        float u   = bf2f(up[(size_t)t * Din]);
        float z   = bf2f(zp[(size_t)t * (2 * Din)]);
        float du = dlt * u;
        float y = 0.f;
        const float4* brow = (const float4*)&Bs[t][0];
        const float4* crow = (const float4*)&Cs[t][0];
        #pragma unroll
        for (int j = 0; j < 4; j++) {
            float4 bv = brow[j];
            float4 cv = crow[j];
            s[4*j+0] = fmaf(exp2f(dlt * An2[4*j+0]), s[4*j+0], du * bv.x);
            y = fmaf(s[4*j+0], cv.x, y);
            s[4*j+1] = fmaf(exp2f(dlt * An2[4*j+1]), s[4*j+1], du * bv.y);
            y = fmaf(s[4*j+1], cv.y, y);
            s[4*j+2] = fmaf(exp2f(dlt * An2[4*j+2]), s[4*j+2], du * bv.z);
            y = fmaf(s[4*j+2], cv.z, y);
            s[4*j+3] = fmaf(exp2f(dlt * An2[4*j+3]), s[4*j+3], du * bv.w);
            y = fmaf(s[4*j+3], cv.w, y);
        }
        y += u * Dv;
        yp[(size_t)t * Din] = f2bf(y * (z * sigmoid_f(z)));
    }
}

// ---------------- launch ----------------
extern "C" void kernel_launch(void* const* d_in, const int* in_sizes, int n_in,
                              void* d_out, int out_size, void* d_ws, size_t ws_size,
                              hipStream_t stream)
{
    const float* x      = (const float*)d_in[0];
    const float* ln_g   = (const float*)d_in[1];
    const float* ln_b   = (const float*)d_in[2];
    const float* W_in   = (const float*)d_in[3];
    const float* conv_w = (const float*)d_in[4];
    const float* conv_b = (const float*)d_in[5];
    const float* W_xprj = (const float*)d_in[6];
    const float* W_dt   = (const float*)d_in[7];
    const float* b_dt   = (const float*)d_in[8];
    const float* A_log  = (const float*)d_in[9];
    const float* D_par  = (const float*)d_in[10];
    const float* W_out  = (const float*)d_in[11];
    float* out = (float*)d_out;

    // ---- workspace layout (~67 MB with aliasing) ----
    unsigned short* delta_bf = (unsigned short*)d_ws;                   // 8MB  [2048,2048] bf16
    unsigned short* xz_bf  = delta_bf + (size_t)Tt * Din;               // 16MB [2048,4096] bf16
    float* outP = (float*)xz_bf;     // alias: xz dead before out-GEMM
    unsigned short* xc_bf  = xz_bf + (size_t)Tt * 2 * Din;              // 8MB
    unsigned short* dbc_bf = xc_bf + (size_t)Tt * Din;                  // 0.5MB [2048,128]
    unsigned short* h_bf   = dbc_bf + (size_t)Tt * 128;                 // 4MB
    unsigned short* yz_bf  = h_bf;   // alias: h_bf+WinT dead after GEMM1
    unsigned short* WinT   = h_bf   + (size_t)Tt * Dmod;                // 8MB
    unsigned short* WoutT  = WinT   + (size_t)(2 * Din) * Dmod;         // 4MB
    unsigned short* WxprjT = WoutT  + (size_t)Dmod * Din;               // 0.5MB
    unsigned short* WdtT   = WxprjT + (size_t)128 * Din;                // 0.25MB
    float* sumd   = (float*)(WdtT + (size_t)Din * RNK);                 // 2MB [B,NC,Din]
    float* xprojP = sumd + (size_t)Bsz * NC * Din;                      // region max(8.4, 16)MB
    unsigned short* Sloc = (unsigned short*)xprojP;  // alias: 16MB bf16 [B,NC,16,Din];
                                                     // xprojP (8.4MB f32) dead before scan_a

    // 0. all weight transposes in one launch (f32 [K,N] -> bf16 [Npad,K])
    transpose_all<<<1632, 256, 0, stream>>>(W_in, WinT, W_out, WoutT, W_xprj, WxprjT, W_dt, WdtT);

    // 1. LayerNorm -> bf16
    ln_kernel<<<Tt, 256, 0, stream>>>(x, ln_g, ln_b, h_bf);

    // 2. xz = h @ W_in  (MFMA, bf16 out)  [2048,1024]x[1024,4096]
    gemm_mfma<0, 1><<<dim3(2 * Din / 128, Tt / 128, 1), 256, 0, stream>>>(
        h_bf, Dmod, WinT, Dmod, xz_bf, 2 * Din, nullptr, nullptr, Tt, 2 * Din, Dmod, 0);

    // 3. x_c = silu(causal_conv(x_in)) -> bf16  (8 ch/thread)
    conv_silu_kernel<<<(Tt * (size_t)Din / 8) / 256, 256, 0, stream>>>(xz_bf, conv_w, conv_b, xc_bf);

    // 4. dbc = x_c @ W_xproj  (split-K 8-way, f32 partials, then reduce->bf16)
    gemm_mfma<0, 0><<<dim3(1, Tt / 128, 8), 256, 0, stream>>>(
        xc_bf, Din, WxprjT, Din, xprojP, 128, nullptr, nullptr, Tt, 128, Din / 8,
        (size_t)Tt * 128);
    reduce_xproj<<<(Tt * 128) / 256, 256, 0, stream>>>(xprojP, dbc_bf);

    // 5. delta = softplus(dt @ W_dt + b_dt) (MFMA, K=64, bf16 out)
    gemm_mfma<1, 1><<<dim3(Din / 128, Tt / 128, 1), 256, 0, stream>>>(
        dbc_bf, 128, WdtT, RNK, delta_bf, Din, nullptr, b_dt, Tt, Din, RNK, 0);

    // 6. selective scan: chunk-parallel 3-pass (NC=128 -> 2048 blocks for a/c)
    scan_a<<<dim3(Din / 256, NC, Bsz), 256, 0, stream>>>(delta_bf, xc_bf, dbc_bf, A_log, Sloc, sumd);
    scan_b<<<dim3(Din / 256, NST, Bsz), 256, 0, stream>>>(A_log, sumd, Sloc);
    scan_c<<<dim3(Din / 256, NC, Bsz), 256, 0, stream>>>(delta_bf, xc_bf, xz_bf, dbc_bf, A_log, D_par, Sloc, yz_bf);

    // 7. out-proj split-K 2-way + residual reduce
    gemm_mfma<0, 0><<<dim3(Dmod / 128, Tt / 128, 2), 256, 0, stream>>>(
        yz_bf, Din, WoutT, Din, outP, Dmod, nullptr, nullptr, Tt, Dmod, Din / 2,
        (size_t)Tt * Dmod);
    reduce_out<<<(Tt * Dmod / 4) / 256, 256, 0, stream>>>(outP, x, out);
}

// Round 12
// 247.568 us; speedup vs baseline: 1.0449x; 1.0449x over previous
//
#include <hip/hip_runtime.h>
#include <hip/hip_bf16.h>
#include <math.h>

// Problem constants (fixed by reference setup_inputs)
constexpr int Bsz  = 2;
constexpr int Lseq = 1024;
constexpr int Dmod = 1024;   // d
constexpr int Din  = 2048;   // Di = 2*d
constexpr int NST  = 16;     // D_STATE
constexpr int RNK  = 64;     // DT_RANK
constexpr int Tt   = Bsz * Lseq;  // 2048 tokens
constexpr int NC   = 64;     // scan chunks (NC=128 was neutral; 64 keeps scan_b short)
constexpr int LC   = Lseq / NC;  // 16 timesteps per chunk

constexpr float L2E = 1.44269504088896341f;   // log2(e)
constexpr float LN2 = 0.69314718055994531f;   // ln(2)

typedef short bf16x8 __attribute__((ext_vector_type(8)));
typedef float f32x4  __attribute__((ext_vector_type(4)));

// fast transcendentals: v_exp_f32 is native 2^x
__device__ __forceinline__ float sigmoid_f(float x) {
    return __builtin_amdgcn_rcpf(1.f + exp2f(-x * L2E));
}
__device__ __forceinline__ float softplus_f(float x) {
    return fmaxf(x, 0.f) + LN2 * log2f(1.f + exp2f(-fabsf(x) * L2E));
}
__device__ __forceinline__ unsigned short f2bf(float f) {
    union { float f; unsigned int u; } v; v.f = f;
    unsigned int r = v.u + 0x7fffu + ((v.u >> 16) & 1u);   // RNE
    return (unsigned short)(r >> 16);
}
__device__ __forceinline__ float bf2f(unsigned short u) {
    union { unsigned int u; float f; } v; v.u = ((unsigned int)u) << 16;
    return v.f;
}

// ---------------- LayerNorm -> bf16 h ----------------
__global__ __launch_bounds__(256) void ln_kernel(
    const float* __restrict__ x, const float* __restrict__ g,
    const float* __restrict__ bta, unsigned short* __restrict__ h)
{
    int row = blockIdx.x;
    const float4* xr = (const float4*)(x + (size_t)row * Dmod);
    float4 v = xr[threadIdx.x];
    float s  = v.x + v.y + v.z + v.w;
    float ss = v.x*v.x + v.y*v.y + v.z*v.z + v.w*v.w;
    #pragma unroll
    for (int o = 1; o < 64; o <<= 1) {
        s  += __shfl_xor(s, o, 64);
        ss += __shfl_xor(ss, o, 64);
    }
    __shared__ float red0[4], red1[4];
    int wid = threadIdx.x >> 6;
    if ((threadIdx.x & 63) == 0) { red0[wid] = s; red1[wid] = ss; }
    __syncthreads();
    s  = red0[0] + red0[1] + red0[2] + red0[3];
    ss = red1[0] + red1[1] + red1[2] + red1[3];
    float mu  = s * (1.f / Dmod);
    float var = ss * (1.f / Dmod) - mu * mu;
    float rs  = rsqrtf(var + 1e-5f);
    float4 gv = ((const float4*)g)[threadIdx.x];
    float4 bv = ((const float4*)bta)[threadIdx.x];
    ushort4 o;
    o.x = f2bf((v.x - mu) * rs * gv.x + bv.x);
    o.y = f2bf((v.y - mu) * rs * gv.y + bv.y);
    o.z = f2bf((v.z - mu) * rs * gv.z + bv.z);
    o.w = f2bf((v.w - mu) * rs * gv.w + bv.w);
    ((ushort4*)(h + (size_t)row * Dmod))[threadIdx.x] = o;
}

// ---- merged transpose+cast for all 4 weights: in[K,N] f32 -> out[Npad,K] bf16 ----
__global__ __launch_bounds__(256) void transpose_all(
    const float* __restrict__ W_in,   unsigned short* __restrict__ WinT,
    const float* __restrict__ W_out,  unsigned short* __restrict__ WoutT,
    const float* __restrict__ W_xprj, unsigned short* __restrict__ WxprjT,
    const float* __restrict__ W_dt,   unsigned short* __restrict__ WdtT)
{
    int bid = blockIdx.x;
    const float* in; unsigned short* outp; int K, N, Npad, bx, by;
    if (bid < 1024)      { in = W_in;   outp = WinT;   K = Dmod; N = 2*Din; Npad = 2*Din; bx = bid & 63; by = bid >> 6; }
    else if (bid < 1536) { bid -= 1024; in = W_out;  outp = WoutT;  K = Din;  N = Dmod;  Npad = Dmod;  bx = bid & 15; by = bid >> 4; }
    else if (bid < 1600) { bid -= 1536; in = W_xprj; outp = WxprjT; K = Din;  N = 96;    Npad = 128;   bx = bid & 1;  by = bid >> 1; }
    else                 { bid -= 1600; in = W_dt;   outp = WdtT;   K = RNK;  N = Din;   Npad = Din;   bx = bid;      by = 0; }

    __shared__ float tile[64][65];
    int bk = by * 64, bn = bx * 64;
    #pragma unroll
    for (int i = 0; i < 16; i++) {
        int k = (threadIdx.x >> 6) + i * 4;
        int n = threadIdx.x & 63;
        int gk = bk + k, gn = bn + n;
        tile[k][n] = (gk < K && gn < N) ? in[(size_t)gk * N + gn] : 0.f;
    }
    __syncthreads();
    #pragma unroll
    for (int i = 0; i < 16; i++) {
        int n = (threadIdx.x >> 6) + i * 4;
        int k = threadIdx.x & 63;
        int gn = bn + n, gk = bk + k;
        if (gn < Npad && gk < K)
            outp[(size_t)gn * K + gk] = f2bf(tile[k][n]);
    }
}

// ---------------- bf16 MFMA GEMM, double-buffered + XCD swizzle (T1) ----------------
template<int EPI, int BF16OUT>
__global__ __launch_bounds__(256) void gemm_mfma(
    const unsigned short* __restrict__ A, int lda,
    const unsigned short* __restrict__ Bt, int ldb,
    void* __restrict__ Cout, int ldc,
    const float* __restrict__ resid, const float* __restrict__ bias,
    int M, int N, int Ksub, size_t pstride)
{
    __shared__ unsigned short As[2][128 * 32];
    __shared__ unsigned short Bs[2][128 * 32];
    int tid = threadIdx.x;

    // T1: XCD-aware remap of the (x,y) plane. All per-slice block counts here
    // are divisible by 8 -> simple bijective form (m157/m204). Per-z-slice.
    int nwg = gridDim.x * gridDim.y;
    int orig = blockIdx.y * gridDim.x + blockIdx.x;
    int swz = orig;
    if ((nwg & 7) == 0) swz = (orig & 7) * (nwg >> 3) + (orig >> 3);
    int bx = swz % gridDim.x, by = swz / gridDim.x;

    int bm = by * 128, bn = bx * 128;
    int kbase = blockIdx.z * Ksub;
    int lane = tid & 63, wid = tid >> 6;
    int wm = (wid & 1) * 64, wn = (wid >> 1) * 64;

    f32x4 acc[4][4] = {};

    int row = tid >> 2;
    int kb  = (tid & 3) * 8;
    unsigned lbase = (unsigned)wid * 1024;

    const unsigned short* Ab0 = A  + (size_t)(bm + row)      * lda + kbase + kb;
    const unsigned short* Ab1 = A  + (size_t)(bm + 64 + row) * lda + kbase + kb;
    const unsigned short* Bb0 = Bt + (size_t)(bn + row)      * ldb + kbase + kb;
    const unsigned short* Bb1 = Bt + (size_t)(bn + 64 + row) * ldb + kbase + kb;

#define STAGE(bufsel, koff) do {                                                          \
    __builtin_amdgcn_global_load_lds(                                                     \
        (const __attribute__((address_space(1))) unsigned int*)(Ab0 + (koff)),            \
        (__attribute__((address_space(3))) unsigned int*)((char*)As + (bufsel) * 8192 + lbase), 16, 0, 0); \
    __builtin_amdgcn_global_load_lds(                                                     \
        (const __attribute__((address_space(1))) unsigned int*)(Ab1 + (koff)),            \
        (__attribute__((address_space(3))) unsigned int*)((char*)As + (bufsel) * 8192 + 4096 + lbase), 16, 0, 0); \
    __builtin_amdgcn_global_load_lds(                                                     \
        (const __attribute__((address_space(1))) unsigned int*)(Bb0 + (koff)),            \
        (__attribute__((address_space(3))) unsigned int*)((char*)Bs + (bufsel) * 8192 + lbase), 16, 0, 0); \
    __builtin_amdgcn_global_load_lds(                                                     \
        (const __attribute__((address_space(1))) unsigned int*)(Bb1 + (koff)),            \
        (__attribute__((address_space(3))) unsigned int*)((char*)Bs + (bufsel) * 8192 + 4096 + lbase), 16, 0, 0); \
} while (0)

    STAGE(0, 0);
    __syncthreads();

    int nt = Ksub / 32;
    int cur = 0;
    for (int t = 0; t < nt; ++t) {
        if (t + 1 < nt) STAGE(cur ^ 1, (t + 1) * 32);
        bf16x8 af[4], bfr[4];
        #pragma unroll
        for (int m = 0; m < 4; m++) {
            int r = wm + m * 16 + (lane & 15);
            af[m] = *(const bf16x8*)((const char*)As + cur * 8192 + r * 64 + (lane >> 4) * 16);
        }
        #pragma unroll
        for (int n = 0; n < 4; n++) {
            int r = wn + n * 16 + (lane & 15);
            bfr[n] = *(const bf16x8*)((const char*)Bs + cur * 8192 + r * 64 + (lane >> 4) * 16);
        }
        #pragma unroll
        for (int m = 0; m < 4; m++)
            #pragma unroll
            for (int n = 0; n < 4; n++)
                acc[m][n] = __builtin_amdgcn_mfma_f32_16x16x32_bf16(af[m], bfr[n], acc[m][n], 0, 0, 0);
        __syncthreads();
        cur ^= 1;
    }
#undef STAGE

    size_t zoff = (size_t)blockIdx.z * pstride;
    #pragma unroll
    for (int m = 0; m < 4; m++) {
        int gm0 = bm + wm + m * 16 + (lane >> 4) * 4;
        #pragma unroll
        for (int n = 0; n < 4; n++) {
            int gn = bn + wn + n * 16 + (lane & 15);
            #pragma unroll
            for (int r = 0; r < 4; r++) {
                int gm = gm0 + r;
                float v = acc[m][n][r];
                if (EPI == 1) v = softplus_f(v + bias[gn]);
                else if (EPI == 2) v += resid[(size_t)gm * ldc + gn];
                if (BF16OUT)
                    ((unsigned short*)Cout)[zoff + (size_t)gm * ldc + gn] = f2bf(v);
                else
                    ((float*)Cout)[zoff + (size_t)gm * ldc + gn] = v;
            }
        }
    }
}

// ---------------- split-K reduces ----------------
__global__ __launch_bounds__(256) void reduce_xproj(
    const float* __restrict__ part, unsigned short* __restrict__ out)
{
    int idx = blockIdx.x * 256 + threadIdx.x;    // < Tt*128
    float s = 0.f;
    #pragma unroll
    for (int z = 0; z < 8; z++) s += part[(size_t)z * Tt * 128 + idx];
    out[idx] = f2bf(s);
}

__global__ __launch_bounds__(256) void reduce_out(
    const float* __restrict__ part, const float* __restrict__ resid,
    float* __restrict__ out)
{
    int idx = blockIdx.x * 256 + threadIdx.x;    // < Tt*Dmod/4
    float4 p0 = ((const float4*)part)[idx];
    float4 p1 = ((const float4*)(part + (size_t)Tt * Dmod))[idx];
    float4 rv = ((const float4*)resid)[idx];
    float4 o;
    o.x = p0.x + p1.x + rv.x;
    o.y = p0.y + p1.y + rv.y;
    o.z = p0.z + p1.z + rv.z;
    o.w = p0.w + p1.w + rv.w;
    ((float4*)out)[idx] = o;
}

// ------- Causal depthwise conv (K=4) + SiLU, 8 channels/thread (bf16x8) -------
__global__ __launch_bounds__(256) void conv_silu_kernel(
    const unsigned short* __restrict__ xz, const float* __restrict__ w,
    const float* __restrict__ cb, unsigned short* __restrict__ xcb)
{
    size_t idx = (size_t)blockIdx.x * 256 + threadIdx.x;   // < Tt*Din/8
    int di8 = (idx * 8) % Din;
    int t   = (idx * 8 / Din) % Lseq;
    int b   = idx * 8 / ((size_t)Din * Lseq);
    const unsigned short* base = xz + (size_t)b * Lseq * (2 * Din) + di8;

    float acc[8];
    float4 cb0 = *(const float4*)(cb + di8);
    float4 cb1 = *(const float4*)(cb + di8 + 4);
    acc[0]=cb0.x; acc[1]=cb0.y; acc[2]=cb0.z; acc[3]=cb0.w;
    acc[4]=cb1.x; acc[5]=cb1.y; acc[6]=cb1.z; acc[7]=cb1.w;

    float4 wv[8];
    #pragma unroll
    for (int j = 0; j < 8; j++) wv[j] = *(const float4*)(w + (di8 + j) * 4);

    #pragma unroll
    for (int k = 0; k < 4; k++) {
        int tt = t - 3 + k;
        if (tt >= 0) {
            bf16x8 rowv = *(const bf16x8*)(base + (size_t)tt * (2 * Din));
            #pragma unroll
            for (int j = 0; j < 8; j++) {
                float wk = (&wv[j].x)[k];
                acc[j] = fmaf(wk, bf2f((unsigned short)rowv[j]), acc[j]);
            }
        }
    }
    bf16x8 outv;
    #pragma unroll
    for (int j = 0; j < 8; j++) {
        float v = acc[j] * sigmoid_f(acc[j]);
        outv[j] = (short)f2bf(v);
    }
    *(bf16x8*)(xcb + idx * 8) = outv;
}

// ---------------- Selective scan: chunk-parallel 3-pass ----------------
__global__ __launch_bounds__(256) void scan_a(
    const unsigned short* __restrict__ delta, const unsigned short* __restrict__ xc,
    const unsigned short* __restrict__ dbc, const float* __restrict__ A_log,
    unsigned short* __restrict__ Sloc, float* __restrict__ sumd_buf)
{
    int tid = threadIdx.x;
    int di = blockIdx.x * 256 + tid;
    int c  = blockIdx.y, b = blockIdx.z;
    int t0 = c * LC;
    __shared__ float Bs[LC][16];
    for (int i = tid; i < LC * 16; i += 256) {
        int tl = i >> 4, n = i & 15;
        Bs[tl][n] = bf2f(dbc[(size_t)(b * Lseq + t0 + tl) * 128 + RNK + n]);
    }
    float An2[16];
    #pragma unroll
    for (int n = 0; n < 16; n++) An2[n] = -expf(A_log[di * NST + n]) * L2E;
    __syncthreads();

    float s[16] = {};
    float sd = 0.f;
    const unsigned short* dp = delta + (size_t)(b * Lseq + t0) * Din + di;
    const unsigned short* up = xc    + (size_t)(b * Lseq + t0) * Din + di;
    #pragma unroll
    for (int t = 0; t < LC; t++) {
        float dlt = bf2f(dp[(size_t)t * Din]);
        float u   = bf2f(up[(size_t)t * Din]);
        sd += dlt;
        float du = dlt * u;
        const float4* brow = (const float4*)&Bs[t][0];
        #pragma unroll
        for (int j = 0; j < 4; j++) {
            float4 bv = brow[j];
            s[4*j+0] = fmaf(exp2f(dlt * An2[4*j+0]), s[4*j+0], du * bv.x);
            s[4*j+1] = fmaf(exp2f(dlt * An2[4*j+1]), s[4*j+1], du * bv.y);
            s[4*j+2] = fmaf(exp2f(dlt * An2[4*j+2]), s[4*j+2], du * bv.z);
            s[4*j+3] = fmaf(exp2f(dlt * An2[4*j+3]), s[4*j+3], du * bv.w);
        }
    }
    size_t base = (size_t)((b * NC + c) * 16) * Din + di;
    #pragma unroll
    for (int n = 0; n < 16; n++) Sloc[base + (size_t)n * Din] = f2bf(s[n]);
    sumd_buf[(size_t)(b * NC + c) * Din + di] = sd;
}

__global__ __launch_bounds__(256) void scan_b(
    const float* __restrict__ A_log, const float* __restrict__ sumd_buf,
    unsigned short* __restrict__ Sloc)
{
    int tid = threadIdx.x;
    int di = blockIdx.x * 256 + tid;
    int n  = blockIdx.y, b = blockIdx.z;
    float An2 = -expf(A_log[di * NST + n]) * L2E;
    float s = 0.f;
    #pragma unroll 4
    for (int c = 0; c < NC; c++) {
        size_t idx = (size_t)((b * NC + c) * 16 + n) * Din + di;
        float sl = bf2f(Sloc[idx]);
        float sd = sumd_buf[(size_t)(b * NC + c) * Din + di];
        Sloc[idx] = f2bf(s);                  // s_in for chunk c
        s = fmaf(exp2f(An2 * sd), s, sl);     // chunk-final state
    }
}

__global__ __launch_bounds__(256) void scan_c(
    const unsigned short* __restrict__ delta, const unsigned short* __restrict__ xc,
    const unsigned short* __restrict__ xz, const unsigned short* __restrict__ dbc,
    const float* __restrict__ A_log, const float* __restrict__ Dp,
    const unsigned short* __restrict__ Sloc,  unsigned short* __restrict__ yz)
{
    int tid = threadIdx.x;
    int di = blockIdx.x * 256 + tid;
    int c  = blockIdx.y, b = blockIdx.z;
    int t0 = c * LC;
    __shared__ float Bs[LC][16], Cs[LC][16];
    for (int i = tid; i < LC * 16; i += 256) {
        int tl = i >> 4, n = i & 15;
        size_t rb = (size_t)(b * Lseq + t0 + tl) * 128;
        Bs[tl][n] = bf2f(dbc[rb + RNK + n]);
        Cs[tl][n] = bf2f(dbc[rb + RNK + NST + n]);
    }
    float An2[16];
    #pragma unroll
    for (int n = 0; n < 16; n++) An2[n] = -expf(A_log[di * NST + n]) * L2E;
    __syncthreads();

    float s[16];
    size_t sbase = (size_t)((b * NC + c) * 16) * Din + di;
    #pragma unroll
    for (int n = 0; n < 16; n++) s[n] = bf2f(Sloc[sbase + (size_t)n * Din]);
    float Dv = Dp[di];

    const unsigned short* dp = delta + (size_t)(b * Lseq + t0) * Din + di;
    const unsigned short* up = xc    + (size_t)(b * Lseq + t0) * Din + di;
    const unsigned short* zp = xz    + (size_t)(b * Lseq + t0) * (2 * Din) + Din + di;
    unsigned short* yp = yz + (size_t)(b * Lseq + t0) * Din + di;
    #pragma unroll
    for (int t = 0; t < LC; t++) {
        float dlt = bf2f(dp[(size_t)t * Din]);
        float u   = bf2f(up[(size_t)t * Din]);
        float z   = bf2f(zp[(size_t)t * (2 * Din)]);
        float du = dlt * u;
        float y = 0.f;
        const float4* brow = (const float4*)&Bs[t][0];
        const float4* crow = (const float4*)&Cs[t][0];
        #pragma unroll
        for (int j = 0; j < 4; j++) {
            float4 bv = brow[j];
            float4 cv = crow[j];
            s[4*j+0] = fmaf(exp2f(dlt * An2[4*j+0]), s[4*j+0], du * bv.x);
            y = fmaf(s[4*j+0], cv.x, y);
            s[4*j+1] = fmaf(exp2f(dlt * An2[4*j+1]), s[4*j+1], du * bv.y);
            y = fmaf(s[4*j+1], cv.y, y);
            s[4*j+2] = fmaf(exp2f(dlt * An2[4*j+2]), s[4*j+2], du * bv.z);
            y = fmaf(s[4*j+2], cv.z, y);
            s[4*j+3] = fmaf(exp2f(dlt * An2[4*j+3]), s[4*j+3], du * bv.w);
            y = fmaf(s[4*j+3], cv.w, y);
        }
        y += u * Dv;
        yp[(size_t)t * Din] = f2bf(y * (z * sigmoid_f(z)));
    }
}

// ---------------- launch ----------------
extern "C" void kernel_launch(void* const* d_in, const int* in_sizes, int n_in,
                              void* d_out, int out_size, void* d_ws, size_t ws_size,
                              hipStream_t stream)
{
    const float* x      = (const float*)d_in[0];
    const float* ln_g   = (const float*)d_in[1];
    const float* ln_b   = (const float*)d_in[2];
    const float* W_in   = (const float*)d_in[3];
    const float* conv_w = (const float*)d_in[4];
    const float* conv_b = (const float*)d_in[5];
    const float* W_xprj = (const float*)d_in[6];
    const float* W_dt   = (const float*)d_in[7];
    const float* b_dt   = (const float*)d_in[8];
    const float* A_log  = (const float*)d_in[9];
    const float* D_par  = (const float*)d_in[10];
    const float* W_out  = (const float*)d_in[11];
    float* out = (float*)d_out;

    // ---- workspace layout (~61 MB with aliasing) ----
    unsigned short* delta_bf = (unsigned short*)d_ws;                   // 8MB  [2048,2048] bf16
    unsigned short* xz_bf  = delta_bf + (size_t)Tt * Din;               // 16MB [2048,4096] bf16
    float* outP = (float*)xz_bf;     // alias: xz dead before out-GEMM
    unsigned short* xc_bf  = xz_bf + (size_t)Tt * 2 * Din;              // 8MB
    unsigned short* dbc_bf = xc_bf + (size_t)Tt * Din;                  // 0.5MB [2048,128]
    unsigned short* h_bf   = dbc_bf + (size_t)Tt * 128;                 // 4MB
    unsigned short* yz_bf  = h_bf;   // alias: h_bf+WinT dead after GEMM1
    unsigned short* WinT   = h_bf   + (size_t)Tt * Dmod;                // 8MB
    unsigned short* WoutT  = WinT   + (size_t)(2 * Din) * Dmod;         // 4MB
    unsigned short* WxprjT = WoutT  + (size_t)Dmod * Din;               // 0.5MB
    unsigned short* WdtT   = WxprjT + (size_t)128 * Din;                // 0.25MB
    float* sumd   = (float*)(WdtT + (size_t)Din * RNK);                 // 1MB [B,NC,Din]
    float* xprojP = sumd + (size_t)Bsz * NC * Din;                      // 8.4MB [8][2048][128] f32
    unsigned short* Sloc = (unsigned short*)xprojP;  // alias: 8.4MB bf16 [B,NC,16,Din]

    // 0. all weight transposes in one launch (f32 [K,N] -> bf16 [Npad,K])
    transpose_all<<<1632, 256, 0, stream>>>(W_in, WinT, W_out, WoutT, W_xprj, WxprjT, W_dt, WdtT);

    // 1. LayerNorm -> bf16
    ln_kernel<<<Tt, 256, 0, stream>>>(x, ln_g, ln_b, h_bf);

    // 2. xz = h @ W_in  (MFMA, bf16 out)  [2048,1024]x[1024,4096]
    gemm_mfma<0, 1><<<dim3(2 * Din / 128, Tt / 128, 1), 256, 0, stream>>>(
        h_bf, Dmod, WinT, Dmod, xz_bf, 2 * Din, nullptr, nullptr, Tt, 2 * Din, Dmod, 0);

    // 3. x_c = silu(causal_conv(x_in)) -> bf16  (8 ch/thread)
    conv_silu_kernel<<<(Tt * (size_t)Din / 8) / 256, 256, 0, stream>>>(xz_bf, conv_w, conv_b, xc_bf);

    // 4. dbc = x_c @ W_xproj  (split-K 8-way, f32 partials, then reduce->bf16)
    gemm_mfma<0, 0><<<dim3(1, Tt / 128, 8), 256, 0, stream>>>(
        xc_bf, Din, WxprjT, Din, xprojP, 128, nullptr, nullptr, Tt, 128, Din / 8,
        (size_t)Tt * 128);
    reduce_xproj<<<(Tt * 128) / 256, 256, 0, stream>>>(xprojP, dbc_bf);

    // 5. delta = softplus(dt @ W_dt + b_dt) (MFMA, K=64, bf16 out)
    gemm_mfma<1, 1><<<dim3(Din / 128, Tt / 128, 1), 256, 0, stream>>>(
        dbc_bf, 128, WdtT, RNK, delta_bf, Din, nullptr, b_dt, Tt, Din, RNK, 0);

    // 6. selective scan: chunk-parallel 3-pass (NC=64)
    scan_a<<<dim3(Din / 256, NC, Bsz), 256, 0, stream>>>(delta_bf, xc_bf, dbc_bf, A_log, Sloc, sumd);
    scan_b<<<dim3(Din / 256, NST, Bsz), 256, 0, stream>>>(A_log, sumd, Sloc);
    scan_c<<<dim3(Din / 256, NC, Bsz), 256, 0, stream>>>(delta_bf, xc_bf, xz_bf, dbc_bf, A_log, D_par, Sloc, yz_bf);

    // 7. out-proj split-K 2-way + residual reduce
    gemm_mfma<0, 0><<<dim3(Dmod / 128, Tt / 128, 2), 256, 0, stream>>>(
        yz_bf, Din, WoutT, Din, outP, Dmod, nullptr, nullptr, Tt, Dmod, Din / 2,
        (size_t)Tt * Dmod);
    reduce_out<<<(Tt * Dmod / 4) / 256, 256, 0, stream>>>(outP, x, out);
}